// Round 1
// 157.894 us; speedup vs baseline: 1.0897x; 1.0897x over previous
//
#include <hip/hip_runtime.h>
#include <math.h>

#define BATCH 2
#define SEQ 2048
#define DMODEL 512
#define NH 8
#define HDIM 64
#define MTOT (BATCH * SEQ)              // 4096
#define QSIZE (BATCH * NH * SEQ * HDIM) // 2097152 elems per tensor
#define WSIZE (DMODEL * DMODEL)         // 262144 elems per weight

typedef __attribute__((ext_vector_type(8))) short bf16x8;
typedef __attribute__((ext_vector_type(4))) float f32x4;

__device__ inline unsigned short f2bf(float f) {
    union { float f; unsigned u; } v; v.f = f;
    unsigned u = v.u;
    u += 0x7fffu + ((u >> 16) & 1u);
    return (unsigned short)(u >> 16);
}
// hardware packed f32->bf16 (RTNE), 1 instr instead of ~10 VALU ops
__device__ inline unsigned pack2(float lo, float hi) {
    unsigned r;
    asm("v_cvt_pk_bf16_f32 %0, %1, %2" : "=v"(r) : "v"(lo), "v"(hi));
    return r;
}

// LDS row stride: 72 elems = 144 B (16B-aligned for ds_read_b128).
#define LSTR 72

// ws layout (bf16 elems):
#define WS_Q   ((size_t)0)
#define WS_K   ((size_t)QSIZE)
#define WS_V   (2 * (size_t)QSIZE)        // [B,H,HD,S] transposed
#define WS_CTX (3 * (size_t)QSIZE)
#define WS_WT  (4 * (size_t)QSIZE)        // 4 transposed weights
#define WS_ABF (4 * (size_t)QSIZE + 4 * (size_t)WSIZE)  // bf16 inputs q,k,v

// ---------------------------------------------------------------------------
// Kernel 0a: transpose + bf16-convert the 4 weight matrices.
// ---------------------------------------------------------------------------
__global__ __launch_bounds__(256) void wt_prep_kernel(
    const float* __restrict__ Wq, const float* __restrict__ Wk,
    const float* __restrict__ Wv, const float* __restrict__ Wo,
    unsigned short* __restrict__ wt)
{
    const int z = blockIdx.z;
    const float* W = (z == 0) ? Wq : (z == 1) ? Wk : (z == 2) ? Wv : Wo;
    unsigned short* Wt = wt + (size_t)z * WSIZE;

    __shared__ float T[32][33];
    const int tid = threadIdx.x;
    const int k0 = blockIdx.x * 32, n0 = blockIdx.y * 32;

    {
        int r = tid >> 3, c = (tid & 7) * 4;
        float4 v = *(const float4*)&W[(size_t)(k0 + r) * DMODEL + n0 + c];
        T[r][c + 0] = v.x; T[r][c + 1] = v.y; T[r][c + 2] = v.z; T[r][c + 3] = v.w;
    }
    __syncthreads();
    {
        int n = tid >> 3, c = (tid & 7) * 4;
        uint2 o;
        o.x = pack2(T[c + 0][n], T[c + 1][n]);
        o.y = pack2(T[c + 2][n], T[c + 3][n]);
        *(uint2*)&Wt[(size_t)(n0 + n) * DMODEL + k0 + c] = o;
    }
}

// ---------------------------------------------------------------------------
// Kernel 0b: convert fp32 inputs -> bf16 (row-major unchanged layout).
// grid (QSIZE/2048 = 1024, 3); 8 elems/thread.
// ---------------------------------------------------------------------------
__global__ __launch_bounds__(256) void inp_prep_kernel(
    const float* __restrict__ qin, const float* __restrict__ kin,
    const float* __restrict__ vin, unsigned short* __restrict__ abf)
{
    const int z = blockIdx.y;
    const float* src = (z == 0) ? qin : (z == 1) ? kin : vin;
    unsigned short* dst = abf + (size_t)z * QSIZE;

    const size_t i = ((size_t)blockIdx.x * 256 + threadIdx.x) * 8;
    float4 f0 = *(const float4*)(src + i);
    float4 f1 = *(const float4*)(src + i + 4);
    uint4 o;
    o.x = pack2(f0.x, f0.y); o.y = pack2(f0.z, f0.w);
    o.z = pack2(f1.x, f1.y); o.w = pack2(f1.z, f1.w);
    *(uint4*)(dst + i) = o;
}

// ---------------------------------------------------------------------------
// Kernel 1: fused QKV projection, bf16 MFMA, 128x128 tiles, bf16 A input.
// Q scaled by 0.125. Q,K stored [B,H,S,HD]; V stored [B,H,HD,S].
// ---------------------------------------------------------------------------
__global__ __launch_bounds__(256) void qkv_mfma_kernel(
    unsigned short* __restrict__ ws,
    const float* __restrict__ bq, const float* __restrict__ bk,
    const float* __restrict__ bv)
{
    const int which = blockIdx.z;
    const unsigned short* A  = ws + WS_ABF + (size_t)which * QSIZE;
    const unsigned short* Wt = ws + WS_WT + (size_t)which * WSIZE;
    const float* bias = (which == 0) ? bq : (which == 1) ? bk : bv;
    unsigned short* out = ws + (size_t)which * QSIZE;

    __shared__ __align__(16) short As[128][LSTR];
    __shared__ __align__(16) short Bs[128][LSTR];

    const int tid = threadIdx.x;
    const int lane = tid & 63, wave = tid >> 6;
    const int lrow = lane & 15, quad = lane >> 4;
    const int m0 = blockIdx.y * 128, n0 = blockIdx.x * 128;

    const int sr = tid >> 1;             // staging row 0..127
    const int sh = (tid & 1) * 32;       // col half (elems)

    f32x4 acc[2][8];
    #pragma unroll
    for (int i = 0; i < 2; ++i)
        #pragma unroll
        for (int n = 0; n < 8; ++n) acc[i][n] = f32x4{0.f, 0.f, 0.f, 0.f};

    for (int k0 = 0; k0 < DMODEL; k0 += 64) {
        __syncthreads();
        {   // stage A: straight bf16 copy
            const unsigned short* ap = A + (size_t)(m0 + sr) * DMODEL + k0 + sh;
            uint4 a0 = *(const uint4*)(ap + 0),  a1 = *(const uint4*)(ap + 8);
            uint4 a2 = *(const uint4*)(ap + 16), a3 = *(const uint4*)(ap + 24);
            *(uint4*)&As[sr][sh + 0]  = a0;
            *(uint4*)&As[sr][sh + 8]  = a1;
            *(uint4*)&As[sr][sh + 16] = a2;
            *(uint4*)&As[sr][sh + 24] = a3;
        }
        {   // stage B: straight bf16 copy from Wt[n][k]
            const unsigned short* wp = Wt + (size_t)(n0 + sr) * DMODEL + k0 + sh;
            uint4 b0 = *(const uint4*)(wp + 0),  b1 = *(const uint4*)(wp + 8);
            uint4 b2 = *(const uint4*)(wp + 16), b3 = *(const uint4*)(wp + 24);
            *(uint4*)&Bs[sr][sh + 0]  = b0;
            *(uint4*)&Bs[sr][sh + 8]  = b1;
            *(uint4*)&Bs[sr][sh + 16] = b2;
            *(uint4*)&Bs[sr][sh + 24] = b3;
        }
        __syncthreads();
        #pragma unroll
        for (int s = 0; s < 2; ++s) {
            bf16x8 af[2];
            #pragma unroll
            for (int i = 0; i < 2; ++i)
                af[i] = *(const bf16x8*)&As[wave * 32 + i * 16 + lrow][s * 32 + quad * 8];
            #pragma unroll
            for (int n = 0; n < 8; ++n) {
                bf16x8 bf = *(const bf16x8*)&Bs[n * 16 + lrow][s * 32 + quad * 8];
                acc[0][n] = __builtin_amdgcn_mfma_f32_16x16x32_bf16(af[0], bf, acc[0][n], 0, 0, 0);
                acc[1][n] = __builtin_amdgcn_mfma_f32_16x16x32_bf16(af[1], bf, acc[1][n], 0, 0, 0);
            }
        }
    }

    if (which < 2) {
        const float scale = (which == 0) ? 0.125f : 1.0f;
        #pragma unroll
        for (int n = 0; n < 8; ++n) {
            const int col = n0 + n * 16 + lrow;
            const int h_ = col >> 6, hd_ = col & 63;
            const float bv_ = bias[col];
            #pragma unroll
            for (int i = 0; i < 2; ++i) {
                #pragma unroll
                for (int r = 0; r < 4; ++r) {
                    const int m = m0 + wave * 32 + i * 16 + quad * 4 + r;
                    const int b_ = m >> 11, s_ = m & (SEQ - 1);
                    const float v = (acc[i][n][r] + bv_) * scale;
                    out[((size_t)((b_ * NH + h_) * SEQ + s_)) * HDIM + hd_] = f2bf(v);
                }
            }
        }
    } else {
        #pragma unroll
        for (int n = 0; n < 8; ++n) {
            const int col = n0 + n * 16 + lrow;
            const int h_ = col >> 6, hd_ = col & 63;
            const float bv_ = bias[col];
            #pragma unroll
            for (int i = 0; i < 2; ++i) {
                const int m = m0 + wave * 32 + i * 16 + quad * 4;
                const int b_ = m >> 11, s_ = m & (SEQ - 1);
                uint2 o;
                o.x = pack2(acc[i][n][0] + bv_, acc[i][n][1] + bv_);
                o.y = pack2(acc[i][n][2] + bv_, acc[i][n][3] + bv_);
                *(uint2*)&out[((size_t)((b_ * NH + h_) * HDIM + hd_)) * SEQ + s_] = o;
            }
        }
    }
}

// ---------------------------------------------------------------------------
// Kernel 2: bf16 MFMA flash attention, S^T formulation, intra-block key-split.
// 512 threads = 8 waves. Waves 0-3 (half 0) process keys [0,1024), waves 4-7
// (half 1) process [1024,2048), each half with private LDS K/V/P buffers.
// Partials (m, l, O) merged through LDS at the end. Grid unchanged (16,32)
// -> 2 blocks/CU x 8 waves = 50% occupancy cap (was 25%).
// Defer-max (T13, THR=8): skip O-rescale when per-tile max doesn't grow.
// grid = (B*H = 16, S/64 = 32), 512 thr.
// ---------------------------------------------------------------------------
#define HSEQ (SEQ / 2)   // 1024 keys per half
#define OSTR 68          // merge O buffer row stride (floats), bank-spread

__global__ __launch_bounds__(512) void attn_mfma_kernel(
    const unsigned short* __restrict__ ws, unsigned short* __restrict__ ctx)
{
    const unsigned short* Q = ws + WS_Q;   // pre-scaled by 0.125
    const unsigned short* K = ws + WS_K;
    const unsigned short* V = ws + WS_V;   // [B,H,HD,S]

    __shared__ __align__(16) short Ks[2][64][LSTR];  // K[key][hd] per half
    __shared__ __align__(16) short Vt[2][64][LSTR];  // V^T[hd][key] per half
    __shared__ __align__(16) short Ps[2][64][LSTR];  // P[q][key] per half

    const int bh = blockIdx.x;
    const int q0 = blockIdx.y * 64;
    const int tid = threadIdx.x;
    const int lane = tid & 63, wave = tid >> 6;
    const int half = wave >> 2, w4 = wave & 3;
    const int lrow = lane & 15, quad = lane >> 4;
    const size_t base = (size_t)bh * SEQ * HDIM;

    // Q as B-operand fragments: B[k=d][n=q]; lane supplies Q[q=lrow][d=quad*8+j]
    const unsigned short* qrow = Q + base + (size_t)(q0 + w4 * 16 + lrow) * HDIM;
    const bf16x8 qb0 = *(const bf16x8*)(qrow + quad * 8);
    const bf16x8 qb1 = *(const bf16x8*)(qrow + 32 + quad * 8);

    float m_prev = -1e30f, l_run = 0.f;
    f32x4 oacc[4];   // O^T: acc[n] rows d = n*16+quad*4+r, col q = lrow
    #pragma unroll
    for (int n = 0; n < 4; ++n) oacc[n] = f32x4{0.f, 0.f, 0.f, 0.f};

    const int t = tid & 255;               // staging thread id within half
    const int kr = t >> 2, kc = (t & 3) * 16;
    const int ktbase = half * HSEQ;

    for (int kt = 0; kt < HSEQ; kt += 64) {
        __syncthreads();
        {   // stage K row-major (per half)
            const unsigned short* kp = K + base + (size_t)(ktbase + kt + kr) * HDIM + kc;
            uint4 k0 = *(const uint4*)kp;
            uint4 k1 = *(const uint4*)(kp + 8);
            *(uint4*)&Ks[half][kr][kc]     = k0;
            *(uint4*)&Ks[half][kr][kc + 8] = k1;
        }
        {   // stage Vt straight copy (per half)
            const unsigned short* vp = V + base + (size_t)kr * SEQ + ktbase + kt + kc;
            uint4 v0 = *(const uint4*)vp;
            uint4 v1 = *(const uint4*)(vp + 8);
            *(uint4*)&Vt[half][kr][kc]     = v0;
            *(uint4*)&Vt[half][kr][kc + 8] = v1;
        }
        __syncthreads();

        // ---- S^T = K·Q^T : st[n] holds keys n*16+quad*4+r, q = lrow ----
        f32x4 st[4];
        #pragma unroll
        for (int n = 0; n < 4; ++n) {
            bf16x8 ka0 = *(const bf16x8*)&Ks[half][n * 16 + lrow][quad * 8];
            bf16x8 ka1 = *(const bf16x8*)&Ks[half][n * 16 + lrow][32 + quad * 8];
            f32x4 z = f32x4{0.f, 0.f, 0.f, 0.f};
            z = __builtin_amdgcn_mfma_f32_16x16x32_bf16(ka0, qb0, z, 0, 0, 0);
            z = __builtin_amdgcn_mfma_f32_16x16x32_bf16(ka1, qb1, z, 0, 0, 0);
            st[n] = z;
        }

        // ---- softmax for q = lrow: all 16 scores are in-lane ----
        float tmax = st[0][0];
        #pragma unroll
        for (int n = 0; n < 4; ++n)
            #pragma unroll
            for (int r = 0; r < 4; ++r) tmax = fmaxf(tmax, st[n][r]);
        tmax = fmaxf(tmax, __shfl_xor(tmax, 16));
        tmax = fmaxf(tmax, __shfl_xor(tmax, 32));

        // defer-max (T13): only rescale when the running max actually grows
        // past THR=8; P stays bounded by e^8, fine in bf16/f32.
        if (!__all(tmax <= m_prev + 8.f)) {
            const float mnew = fmaxf(m_prev, tmax);
            const float alpha = __expf(m_prev - mnew);
            l_run *= alpha;
            #pragma unroll
            for (int n = 0; n < 4; ++n) {
                oacc[n][0] *= alpha; oacc[n][1] *= alpha;
                oacc[n][2] *= alpha; oacc[n][3] *= alpha;
            }
            m_prev = mnew;
        }

        float p[4][4];
        float tsum = 0.f;
        #pragma unroll
        for (int n = 0; n < 4; ++n)
            #pragma unroll
            for (int r = 0; r < 4; ++r) {
                p[n][r] = __expf(st[n][r] - m_prev);
                tsum += p[n][r];
            }
        tsum += __shfl_xor(tsum, 16);
        tsum += __shfl_xor(tsum, 32);
        l_run += tsum;

        // write P[q][key]: row = w4*16+lrow, cols n*16+quad*4 (+0..3)
        #pragma unroll
        for (int n = 0; n < 4; ++n) {
            uint2 o;
            o.x = pack2(p[n][0], p[n][1]);
            o.y = pack2(p[n][2], p[n][3]);
            *(uint2*)&Ps[half][w4 * 16 + lrow][n * 16 + quad * 4] = o;
        }
        // Ps rows are wave-private: no barrier (lgkmcnt ordering suffices).

        // ---- O^T += V^T·P^T ----
        bf16x8 pb0 = *(const bf16x8*)&Ps[half][w4 * 16 + lrow][quad * 8];
        bf16x8 pb1 = *(const bf16x8*)&Ps[half][w4 * 16 + lrow][32 + quad * 8];
        #pragma unroll
        for (int n = 0; n < 4; ++n) {
            bf16x8 va0 = *(const bf16x8*)&Vt[half][n * 16 + lrow][quad * 8];
            bf16x8 va1 = *(const bf16x8*)&Vt[half][n * 16 + lrow][32 + quad * 8];
            oacc[n] = __builtin_amdgcn_mfma_f32_16x16x32_bf16(va0, pb0, oacc[n], 0, 0, 0);
            oacc[n] = __builtin_amdgcn_mfma_f32_16x16x32_bf16(va1, pb1, oacc[n], 0, 0, 0);
        }
    }

    // ---- merge halves through LDS, then normalize + write ctx ----
    __syncthreads();   // all waves done reading Ks/Vt/Ps
    float* Obuf = (float*)&Ks[0][0][0];   // [4 pairs][16 q][OSTR] = 17408 B (fits in Ks)
    float* Mbuf = (float*)&Ps[0][0][0];   // [0..63] = m1, [64..127] = l1

    if (half == 1) {
        float* ob = Obuf + (size_t)w4 * (16 * OSTR) + (size_t)lrow * OSTR;
        #pragma unroll
        for (int n = 0; n < 4; ++n)
            *(f32x4*)&ob[n * 16 + quad * 4] = oacc[n];
        if (quad == 0) {
            Mbuf[w4 * 16 + lrow]      = m_prev;
            Mbuf[64 + w4 * 16 + lrow] = l_run;
        }
    }
    __syncthreads();
    if (half == 0) {
        const float m1 = Mbuf[w4 * 16 + lrow];
        const float l1 = Mbuf[64 + w4 * 16 + lrow];
        const float M  = fmaxf(m_prev, m1);
        const float a0 = __expf(m_prev - M), a1 = __expf(m1 - M);
        const float inv = 1.f / (l_run * a0 + l1 * a1);
        const float s0 = a0 * inv, s1 = a1 * inv;
        const float* ob = Obuf + (size_t)w4 * (16 * OSTR) + (size_t)lrow * OSTR;

        const int b_ = bh >> 3, h_ = bh & 7;
        const int qg = q0 + w4 * 16 + lrow;
        unsigned short* crow = ctx + ((size_t)(b_ * SEQ + qg)) * DMODEL + h_ * HDIM;
        #pragma unroll
        for (int n = 0; n < 4; ++n) {
            f32x4 o1 = *(const f32x4*)&ob[n * 16 + quad * 4];
            uint2 o;
            o.x = pack2(oacc[n][0] * s0 + o1[0] * s1, oacc[n][1] * s0 + o1[1] * s1);
            o.y = pack2(oacc[n][2] * s0 + o1[2] * s1, oacc[n][3] * s0 + o1[3] * s1);
            *(uint2*)&crow[n * 16 + quad * 4] = o;
        }
    }
}

// ---------------------------------------------------------------------------
// Kernel 3: output projection, bf16 MFMA, 128x64 tiles.
// ---------------------------------------------------------------------------
__global__ __launch_bounds__(256) void out_proj_mfma_kernel(
    const unsigned short* __restrict__ ws, const float* __restrict__ bo,
    float* __restrict__ out)
{
    const unsigned short* ctx = ws + WS_CTX;
    const unsigned short* Wt  = ws + WS_WT + 3 * (size_t)WSIZE;

    __shared__ __align__(16) short As[128][LSTR];
    __shared__ __align__(16) short Bs[64][LSTR];

    const int tid = threadIdx.x;
    const int lane = tid & 63, wave = tid >> 6;
    const int lrow = lane & 15, quad = lane >> 4;
    const int m0 = blockIdx.y * 128, n0 = blockIdx.x * 64;

    const int sr = tid >> 1, sh = (tid & 1) * 32;
    const int br = tid >> 2, bqr = (tid & 3) * 16;

    f32x4 acc[2][4];
    #pragma unroll
    for (int i = 0; i < 2; ++i)
        #pragma unroll
        for (int n = 0; n < 4; ++n) acc[i][n] = f32x4{0.f, 0.f, 0.f, 0.f};

    for (int k0 = 0; k0 < DMODEL; k0 += 64) {
        __syncthreads();
        {
            const unsigned short* ap = ctx + (size_t)(m0 + sr) * DMODEL + k0 + sh;
            uint4 c0 = *(const uint4*)(ap + 0),  c1 = *(const uint4*)(ap + 8);
            uint4 c2 = *(const uint4*)(ap + 16), c3 = *(const uint4*)(ap + 24);
            *(uint4*)&As[sr][sh + 0]  = c0;
            *(uint4*)&As[sr][sh + 8]  = c1;
            *(uint4*)&As[sr][sh + 16] = c2;
            *(uint4*)&As[sr][sh + 24] = c3;
        }
        {
            const unsigned short* wp = Wt + (size_t)(n0 + br) * DMODEL + k0 + bqr;
            uint4 b0 = *(const uint4*)wp;
            uint4 b1 = *(const uint4*)(wp + 8);
            *(uint4*)&Bs[br][bqr]     = b0;
            *(uint4*)&Bs[br][bqr + 8] = b1;
        }
        __syncthreads();
        #pragma unroll
        for (int s = 0; s < 2; ++s) {
            bf16x8 af[2];
            #pragma unroll
            for (int i = 0; i < 2; ++i)
                af[i] = *(const bf16x8*)&As[wave * 32 + i * 16 + lrow][s * 32 + quad * 8];
            #pragma unroll
            for (int n = 0; n < 4; ++n) {
                bf16x8 bf = *(const bf16x8*)&Bs[n * 16 + lrow][s * 32 + quad * 8];
                acc[0][n] = __builtin_amdgcn_mfma_f32_16x16x32_bf16(af[0], bf, acc[0][n], 0, 0, 0);
                acc[1][n] = __builtin_amdgcn_mfma_f32_16x16x32_bf16(af[1], bf, acc[1][n], 0, 0, 0);
            }
        }
    }

    #pragma unroll
    for (int n = 0; n < 4; ++n) {
        const int col = n0 + n * 16 + lrow;
        const float bv_ = bo[col];
        #pragma unroll
        for (int i = 0; i < 2; ++i) {
            #pragma unroll
            for (int r = 0; r < 4; ++r) {
                const int m = m0 + wave * 32 + i * 16 + quad * 4 + r;
                out[(size_t)m * DMODEL + col] = acc[i][n][r] + bv_;
            }
        }
    }
}

// ---------------------------------------------------------------------------
extern "C" void kernel_launch(void* const* d_in, const int* in_sizes, int n_in,
                              void* d_out, int out_size, void* d_ws, size_t ws_size,
                              hipStream_t stream)
{
    const float* qin = (const float*)d_in[0];
    const float* kin = (const float*)d_in[1];
    const float* vin = (const float*)d_in[2];
    const float* Wq  = (const float*)d_in[3];
    const float* bq  = (const float*)d_in[4];
    const float* Wk  = (const float*)d_in[5];
    const float* bk  = (const float*)d_in[6];
    const float* Wv  = (const float*)d_in[7];
    const float* bv  = (const float*)d_in[8];
    const float* Wo  = (const float*)d_in[9];
    const float* bo  = (const float*)d_in[10];

    unsigned short* ws = (unsigned short*)d_ws;
    float* out = (float*)d_out;

    dim3 gw(DMODEL / 32, DMODEL / 32, 4);
    wt_prep_kernel<<<gw, 256, 0, stream>>>(Wq, Wk, Wv, Wo, ws + WS_WT);

    dim3 gi(QSIZE / (256 * 8), 3);
    inp_prep_kernel<<<gi, 256, 0, stream>>>(qin, kin, vin, ws + WS_ABF);

    dim3 gp(DMODEL / 128, MTOT / 128, 3);
    qkv_mfma_kernel<<<gp, 256, 0, stream>>>(ws, bq, bk, bv);

    dim3 ga(BATCH * NH, SEQ / 64);
    attn_mfma_kernel<<<ga, 512, 0, stream>>>(ws, ws + WS_CTX);

    dim3 go(DMODEL / 64, MTOT / 128);
    out_proj_mfma_kernel<<<go, 256, 0, stream>>>(ws, bo, out);
}

// Round 2
// 147.742 us; speedup vs baseline: 1.1646x; 1.0687x over previous
//
#include <hip/hip_runtime.h>
#include <math.h>

#define BATCH 2
#define SEQ 2048
#define DMODEL 512
#define NH 8
#define HDIM 64
#define MTOT (BATCH * SEQ)              // 4096
#define QSIZE (BATCH * NH * SEQ * HDIM) // 2097152 elems per tensor
#define WSIZE (DMODEL * DMODEL)         // 262144 elems per weight

typedef __attribute__((ext_vector_type(8))) short bf16x8;
typedef __attribute__((ext_vector_type(4))) float f32x4;

__device__ inline unsigned short f2bf(float f) {
    union { float f; unsigned u; } v; v.f = f;
    unsigned u = v.u;
    u += 0x7fffu + ((u >> 16) & 1u);
    return (unsigned short)(u >> 16);
}
// hardware packed f32->bf16 (RTNE), 1 instr instead of ~10 VALU ops
__device__ inline unsigned pack2(float lo, float hi) {
    unsigned r;
    asm("v_cvt_pk_bf16_f32 %0, %1, %2" : "=v"(r) : "v"(lo), "v"(hi));
    return r;
}

// LDS row stride: 72 elems = 144 B (16B-aligned for ds_read_b128).
#define LSTR 72

// ws layout (bf16 elems):
#define WS_Q   ((size_t)0)
#define WS_K   ((size_t)QSIZE)
#define WS_V   (2 * (size_t)QSIZE)        // [B,H,HD,S] transposed
#define WS_CTX (3 * (size_t)QSIZE)
#define WS_WT  (4 * (size_t)QSIZE)        // 4 transposed weights
#define WS_ABF (4 * (size_t)QSIZE + 4 * (size_t)WSIZE)  // bf16 inputs q,k,v

// ---------------------------------------------------------------------------
// Kernel 0a: transpose + bf16-convert the 4 weight matrices.
// ---------------------------------------------------------------------------
__global__ __launch_bounds__(256) void wt_prep_kernel(
    const float* __restrict__ Wq, const float* __restrict__ Wk,
    const float* __restrict__ Wv, const float* __restrict__ Wo,
    unsigned short* __restrict__ wt)
{
    const int z = blockIdx.z;
    const float* W = (z == 0) ? Wq : (z == 1) ? Wk : (z == 2) ? Wv : Wo;
    unsigned short* Wt = wt + (size_t)z * WSIZE;

    __shared__ float T[32][33];
    const int tid = threadIdx.x;
    const int k0 = blockIdx.x * 32, n0 = blockIdx.y * 32;

    {
        int r = tid >> 3, c = (tid & 7) * 4;
        float4 v = *(const float4*)&W[(size_t)(k0 + r) * DMODEL + n0 + c];
        T[r][c + 0] = v.x; T[r][c + 1] = v.y; T[r][c + 2] = v.z; T[r][c + 3] = v.w;
    }
    __syncthreads();
    {
        int n = tid >> 3, c = (tid & 7) * 4;
        uint2 o;
        o.x = pack2(T[c + 0][n], T[c + 1][n]);
        o.y = pack2(T[c + 2][n], T[c + 3][n]);
        *(uint2*)&Wt[(size_t)(n0 + n) * DMODEL + k0 + c] = o;
    }
}

// ---------------------------------------------------------------------------
// Kernel 0b: convert fp32 inputs -> bf16 (row-major unchanged layout).
// grid (QSIZE/2048 = 1024, 3); 8 elems/thread.
// ---------------------------------------------------------------------------
__global__ __launch_bounds__(256) void inp_prep_kernel(
    const float* __restrict__ qin, const float* __restrict__ kin,
    const float* __restrict__ vin, unsigned short* __restrict__ abf)
{
    const int z = blockIdx.y;
    const float* src = (z == 0) ? qin : (z == 1) ? kin : vin;
    unsigned short* dst = abf + (size_t)z * QSIZE;

    const size_t i = ((size_t)blockIdx.x * 256 + threadIdx.x) * 8;
    float4 f0 = *(const float4*)(src + i);
    float4 f1 = *(const float4*)(src + i + 4);
    uint4 o;
    o.x = pack2(f0.x, f0.y); o.y = pack2(f0.z, f0.w);
    o.z = pack2(f1.x, f1.y); o.w = pack2(f1.z, f1.w);
    *(uint4*)(dst + i) = o;
}

// ---------------------------------------------------------------------------
// Kernel 1: fused QKV projection, bf16 MFMA, 128x128 tiles, bf16 A input.
// Q scaled by 0.125. Q,K stored [B,H,S,HD]; V stored [B,H,HD,S].
// ---------------------------------------------------------------------------
__global__ __launch_bounds__(256) void qkv_mfma_kernel(
    unsigned short* __restrict__ ws,
    const float* __restrict__ bq, const float* __restrict__ bk,
    const float* __restrict__ bv)
{
    const int which = blockIdx.z;
    const unsigned short* A  = ws + WS_ABF + (size_t)which * QSIZE;
    const unsigned short* Wt = ws + WS_WT + (size_t)which * WSIZE;
    const float* bias = (which == 0) ? bq : (which == 1) ? bk : bv;
    unsigned short* out = ws + (size_t)which * QSIZE;

    __shared__ __align__(16) short As[128][LSTR];
    __shared__ __align__(16) short Bs[128][LSTR];

    const int tid = threadIdx.x;
    const int lane = tid & 63, wave = tid >> 6;
    const int lrow = lane & 15, quad = lane >> 4;
    const int m0 = blockIdx.y * 128, n0 = blockIdx.x * 128;

    const int sr = tid >> 1;             // staging row 0..127
    const int sh = (tid & 1) * 32;       // col half (elems)

    f32x4 acc[2][8];
    #pragma unroll
    for (int i = 0; i < 2; ++i)
        #pragma unroll
        for (int n = 0; n < 8; ++n) acc[i][n] = f32x4{0.f, 0.f, 0.f, 0.f};

    for (int k0 = 0; k0 < DMODEL; k0 += 64) {
        __syncthreads();
        {   // stage A: straight bf16 copy
            const unsigned short* ap = A + (size_t)(m0 + sr) * DMODEL + k0 + sh;
            uint4 a0 = *(const uint4*)(ap + 0),  a1 = *(const uint4*)(ap + 8);
            uint4 a2 = *(const uint4*)(ap + 16), a3 = *(const uint4*)(ap + 24);
            *(uint4*)&As[sr][sh + 0]  = a0;
            *(uint4*)&As[sr][sh + 8]  = a1;
            *(uint4*)&As[sr][sh + 16] = a2;
            *(uint4*)&As[sr][sh + 24] = a3;
        }
        {   // stage B: straight bf16 copy from Wt[n][k]
            const unsigned short* wp = Wt + (size_t)(n0 + sr) * DMODEL + k0 + sh;
            uint4 b0 = *(const uint4*)(wp + 0),  b1 = *(const uint4*)(wp + 8);
            uint4 b2 = *(const uint4*)(wp + 16), b3 = *(const uint4*)(wp + 24);
            *(uint4*)&Bs[sr][sh + 0]  = b0;
            *(uint4*)&Bs[sr][sh + 8]  = b1;
            *(uint4*)&Bs[sr][sh + 16] = b2;
            *(uint4*)&Bs[sr][sh + 24] = b3;
        }
        __syncthreads();
        #pragma unroll
        for (int s = 0; s < 2; ++s) {
            bf16x8 af[2];
            #pragma unroll
            for (int i = 0; i < 2; ++i)
                af[i] = *(const bf16x8*)&As[wave * 32 + i * 16 + lrow][s * 32 + quad * 8];
            #pragma unroll
            for (int n = 0; n < 8; ++n) {
                bf16x8 bf = *(const bf16x8*)&Bs[n * 16 + lrow][s * 32 + quad * 8];
                acc[0][n] = __builtin_amdgcn_mfma_f32_16x16x32_bf16(af[0], bf, acc[0][n], 0, 0, 0);
                acc[1][n] = __builtin_amdgcn_mfma_f32_16x16x32_bf16(af[1], bf, acc[1][n], 0, 0, 0);
            }
        }
    }

    if (which < 2) {
        const float scale = (which == 0) ? 0.125f : 1.0f;
        #pragma unroll
        for (int n = 0; n < 8; ++n) {
            const int col = n0 + n * 16 + lrow;
            const int h_ = col >> 6, hd_ = col & 63;
            const float bv_ = bias[col];
            #pragma unroll
            for (int i = 0; i < 2; ++i) {
                #pragma unroll
                for (int r = 0; r < 4; ++r) {
                    const int m = m0 + wave * 32 + i * 16 + quad * 4 + r;
                    const int b_ = m >> 11, s_ = m & (SEQ - 1);
                    const float v = (acc[i][n][r] + bv_) * scale;
                    out[((size_t)((b_ * NH + h_) * SEQ + s_)) * HDIM + hd_] = f2bf(v);
                }
            }
        }
    } else {
        #pragma unroll
        for (int n = 0; n < 8; ++n) {
            const int col = n0 + n * 16 + lrow;
            const int h_ = col >> 6, hd_ = col & 63;
            const float bv_ = bias[col];
            #pragma unroll
            for (int i = 0; i < 2; ++i) {
                const int m = m0 + wave * 32 + i * 16 + quad * 4;
                const int b_ = m >> 11, s_ = m & (SEQ - 1);
                uint2 o;
                o.x = pack2(acc[i][n][0] + bv_, acc[i][n][1] + bv_);
                o.y = pack2(acc[i][n][2] + bv_, acc[i][n][3] + bv_);
                *(uint2*)&out[((size_t)((b_ * NH + h_) * HDIM + hd_)) * SEQ + s_] = o;
            }
        }
    }
}

// ---------------------------------------------------------------------------
// Kernel 2: bf16 MFMA flash attention, S^T formulation, intra-block key-split,
// double-buffered K/V staging (one barrier per tile, loads issued a full
// compute phase ahead), ZERO-SHUFFLE P: Vt columns are staged permuted
//   tau(k): k = n*16+4q+r  ->  (n>=2 ? 32:0) + 8q + 4*(n&1) + r
// so each lane's in-register p[n][r] values are already in the exact PV
// B-fragment slots (8 cvt_pk, no Ps LDS buffer, no shuffles).
// XCD swizzle: blocks sharing (b,h) land on the same XCD -> K/V L2-resident.
// grid = (16, 32) decoded via swizzle, 512 thr (8 waves: 2 key-halves x 4 q).
// ---------------------------------------------------------------------------
#define HSEQ (SEQ / 2)   // 1024 keys per half
#define NT   (HSEQ / 64) // 16 tiles per half
#define OSTR 68          // merge O buffer row stride (floats), bank-spread

__global__ __launch_bounds__(512) void attn_mfma_kernel(
    const unsigned short* __restrict__ ws, unsigned short* __restrict__ ctx)
{
    const unsigned short* Q = ws + WS_Q;   // pre-scaled by 0.125
    const unsigned short* K = ws + WS_K;
    const unsigned short* V = ws + WS_V;   // [B,H,HD,S]

    __shared__ __align__(16) short Ks[2][2][64][LSTR];  // [half][buf][key][hd]
    __shared__ __align__(16) short Vt[2][2][64][LSTR];  // [half][buf][hd][perm key]

    // XCD-aware swizzle: bid mod 8 == bh mod 8 -> all 32 q-tiles of one (b,h)
    // share an XCD; its 1.25 MB of Q/K/V fits in the 4 MB per-XCD L2.
    const int lin = blockIdx.x + 16 * blockIdx.y;          // 0..511
    const int bh  = (lin & 7) + 8 * (lin >> 8);
    const int q0  = ((lin >> 3) & 31) * 64;

    const int tid = threadIdx.x;
    const int lane = tid & 63, wave = tid >> 6;
    const int half = wave >> 2, w4 = wave & 3;
    const int lrow = lane & 15, quad = lane >> 4;
    const size_t base = (size_t)bh * SEQ * HDIM;

    // Q as B-operand fragments: lane supplies Q[q=lrow][d=quad*8+j]
    const unsigned short* qrow = Q + base + (size_t)(q0 + w4 * 16 + lrow) * HDIM;
    const bf16x8 qb0 = *(const bf16x8*)(qrow + quad * 8);
    const bf16x8 qb1 = *(const bf16x8*)(qrow + 32 + quad * 8);

    float m_prev = -1e30f, l_run = 0.f;
    f32x4 oacc[4];   // O^T: acc[n] rows d = n*16+quad*4+r, col q = lrow
    #pragma unroll
    for (int n = 0; n < 4; ++n) oacc[n] = f32x4{0.f, 0.f, 0.f, 0.f};

    // staging geometry (256 threads per half)
    const int t  = tid & 255;
    const int kr = t >> 2;                  // row 0..63
    const int kc = (t & 3) * 16;            // 16 consecutive elems
    const int n_ = t & 3;                   // V: which key-group of 16
    const int c0 = ((n_ >= 2) ? 32 : 0) + (n_ & 1) * 4;  // permuted col base
    const int ktbase = half * HSEQ;

    const unsigned short* kptr = K + base + (size_t)(ktbase + kr) * HDIM + kc;
    const unsigned short* vptr = V + base + (size_t)kr * SEQ + ktbase + kc;

    uint4 kA, kB, vA, vB;
#define LOADT(TI) do { \
        const unsigned short* kp = kptr + (size_t)(TI) * 64 * HDIM; \
        const unsigned short* vp = vptr + (TI) * 64; \
        kA = *(const uint4*)kp; kB = *(const uint4*)(kp + 8); \
        vA = *(const uint4*)vp; vB = *(const uint4*)(vp + 8); \
    } while (0)
#define WRITET(BUF) do { \
        *(uint4*)&Ks[half][BUF][kr][kc]     = kA; \
        *(uint4*)&Ks[half][BUF][kr][kc + 8] = kB; \
        uint2 w0; w0.x = vA.x; w0.y = vA.y; \
        uint2 w1; w1.x = vA.z; w1.y = vA.w; \
        uint2 w2; w2.x = vB.x; w2.y = vB.y; \
        uint2 w3; w3.x = vB.z; w3.y = vB.w; \
        *(uint2*)&Vt[half][BUF][kr][c0]      = w0; \
        *(uint2*)&Vt[half][BUF][kr][c0 + 8]  = w1; \
        *(uint2*)&Vt[half][BUF][kr][c0 + 16] = w2; \
        *(uint2*)&Vt[half][BUF][kr][c0 + 24] = w3; \
    } while (0)

    // prologue: tile 0 -> buf 0, issue tile-1 loads
    LOADT(0);
    WRITET(0);
    LOADT(1);

    #pragma unroll 2
    for (int ti = 0; ti < NT; ++ti) {
        const int cur = ti & 1;
        __syncthreads();   // buf[cur] ready; buf[cur^1] free for rewrite

        // ---- S^T = K·Q^T : st[n] holds keys n*16+quad*4+r, q = lrow ----
        f32x4 st[4];
        __builtin_amdgcn_s_setprio(1);
        #pragma unroll
        for (int n = 0; n < 4; ++n) {
            bf16x8 ka0 = *(const bf16x8*)&Ks[half][cur][n * 16 + lrow][quad * 8];
            bf16x8 ka1 = *(const bf16x8*)&Ks[half][cur][n * 16 + lrow][32 + quad * 8];
            f32x4 z = f32x4{0.f, 0.f, 0.f, 0.f};
            z = __builtin_amdgcn_mfma_f32_16x16x32_bf16(ka0, qb0, z, 0, 0, 0);
            z = __builtin_amdgcn_mfma_f32_16x16x32_bf16(ka1, qb1, z, 0, 0, 0);
            st[n] = z;
        }
        __builtin_amdgcn_s_setprio(0);

        // ---- softmax for q = lrow: all 16 scores in-lane ----
        float tmax = st[0][0];
        #pragma unroll
        for (int n = 0; n < 4; ++n)
            #pragma unroll
            for (int r = 0; r < 4; ++r) tmax = fmaxf(tmax, st[n][r]);
        tmax = fmaxf(tmax, __shfl_xor(tmax, 16));
        tmax = fmaxf(tmax, __shfl_xor(tmax, 32));

        // defer-max (T13, THR=8): rescale only when max actually grows.
        if (!__all(tmax <= m_prev + 8.f)) {
            const float mnew = fmaxf(m_prev, tmax);
            const float alpha = __expf(m_prev - mnew);
            l_run *= alpha;
            #pragma unroll
            for (int n = 0; n < 4; ++n) {
                oacc[n][0] *= alpha; oacc[n][1] *= alpha;
                oacc[n][2] *= alpha; oacc[n][3] *= alpha;
            }
            m_prev = mnew;
        }

        float p[4][4];
        float tsum = 0.f;
        #pragma unroll
        for (int n = 0; n < 4; ++n)
            #pragma unroll
            for (int r = 0; r < 4; ++r) {
                p[n][r] = __expf(st[n][r] - m_prev);
                tsum += p[n][r];
            }
        tsum += __shfl_xor(tsum, 16);
        tsum += __shfl_xor(tsum, 32);
        l_run += tsum;

        // ---- P -> PV B-fragments, fully in-register (zero-shuffle via tau) --
        union { unsigned w[4]; bf16x8 v; } U0, U1;
        U0.w[0] = pack2(p[0][0], p[0][1]); U0.w[1] = pack2(p[0][2], p[0][3]);
        U0.w[2] = pack2(p[1][0], p[1][1]); U0.w[3] = pack2(p[1][2], p[1][3]);
        U1.w[0] = pack2(p[2][0], p[2][1]); U1.w[1] = pack2(p[2][2], p[2][3]);
        U1.w[2] = pack2(p[3][0], p[3][1]); U1.w[3] = pack2(p[3][2], p[3][3]);

        // ---- O^T += V^T·P^T ----
        __builtin_amdgcn_s_setprio(1);
        #pragma unroll
        for (int n = 0; n < 4; ++n) {
            bf16x8 va0 = *(const bf16x8*)&Vt[half][cur][n * 16 + lrow][quad * 8];
            bf16x8 va1 = *(const bf16x8*)&Vt[half][cur][n * 16 + lrow][32 + quad * 8];
            oacc[n] = __builtin_amdgcn_mfma_f32_16x16x32_bf16(va0, U0.v, oacc[n], 0, 0, 0);
            oacc[n] = __builtin_amdgcn_mfma_f32_16x16x32_bf16(va1, U1.v, oacc[n], 0, 0, 0);
        }
        __builtin_amdgcn_s_setprio(0);

        // ---- write tile ti+1 (already in regs) to the other buffer,
        //      then issue loads for tile ti+2 ----
        if (ti < NT - 1) WRITET(cur ^ 1);
        if (ti < NT - 2) LOADT(ti + 2);
    }
#undef LOADT
#undef WRITET

    // ---- merge halves through LDS, then normalize + write ctx ----
    __syncthreads();   // all waves done reading Ks/Vt
    float* Obuf = (float*)&Ks[0][0][0][0];  // 4*16*OSTR*4 = 17408 B
    float* Mbuf = (float*)&Vt[0][0][0][0];  // 128 floats

    if (half == 1) {
        float* ob = Obuf + (size_t)w4 * (16 * OSTR) + (size_t)lrow * OSTR;
        #pragma unroll
        for (int n = 0; n < 4; ++n)
            *(f32x4*)&ob[n * 16 + quad * 4] = oacc[n];
        if (quad == 0) {
            Mbuf[w4 * 16 + lrow]      = m_prev;
            Mbuf[64 + w4 * 16 + lrow] = l_run;
        }
    }
    __syncthreads();
    if (half == 0) {
        const float m1 = Mbuf[w4 * 16 + lrow];
        const float l1 = Mbuf[64 + w4 * 16 + lrow];
        const float M  = fmaxf(m_prev, m1);
        const float a0 = __expf(m_prev - M), a1 = __expf(m1 - M);
        const float inv = 1.f / (l_run * a0 + l1 * a1);
        const float s0 = a0 * inv, s1 = a1 * inv;
        const float* ob = Obuf + (size_t)w4 * (16 * OSTR) + (size_t)lrow * OSTR;

        const int b_ = bh >> 3, h_ = bh & 7;
        const int qg = q0 + w4 * 16 + lrow;
        unsigned short* crow = ctx + ((size_t)(b_ * SEQ + qg)) * DMODEL + h_ * HDIM;
        #pragma unroll
        for (int n = 0; n < 4; ++n) {
            f32x4 o1 = *(const f32x4*)&ob[n * 16 + quad * 4];
            uint2 o;
            o.x = pack2(oacc[n][0] * s0 + o1[0] * s1, oacc[n][1] * s0 + o1[1] * s1);
            o.y = pack2(oacc[n][2] * s0 + o1[2] * s1, oacc[n][3] * s0 + o1[3] * s1);
            *(uint2*)&crow[n * 16 + quad * 4] = o;
        }
    }
}

// ---------------------------------------------------------------------------
// Kernel 3: output projection, bf16 MFMA, 128x64 tiles.
// ---------------------------------------------------------------------------
__global__ __launch_bounds__(256) void out_proj_mfma_kernel(
    const unsigned short* __restrict__ ws, const float* __restrict__ bo,
    float* __restrict__ out)
{
    const unsigned short* ctx = ws + WS_CTX;
    const unsigned short* Wt  = ws + WS_WT + 3 * (size_t)WSIZE;

    __shared__ __align__(16) short As[128][LSTR];
    __shared__ __align__(16) short Bs[64][LSTR];

    const int tid = threadIdx.x;
    const int lane = tid & 63, wave = tid >> 6;
    const int lrow = lane & 15, quad = lane >> 4;
    const int m0 = blockIdx.y * 128, n0 = blockIdx.x * 64;

    const int sr = tid >> 1, sh = (tid & 1) * 32;
    const int br = tid >> 2, bqr = (tid & 3) * 16;

    f32x4 acc[2][4];
    #pragma unroll
    for (int i = 0; i < 2; ++i)
        #pragma unroll
        for (int n = 0; n < 4; ++n) acc[i][n] = f32x4{0.f, 0.f, 0.f, 0.f};

    for (int k0 = 0; k0 < DMODEL; k0 += 64) {
        __syncthreads();
        {
            const unsigned short* ap = ctx + (size_t)(m0 + sr) * DMODEL + k0 + sh;
            uint4 c0 = *(const uint4*)(ap + 0),  c1 = *(const uint4*)(ap + 8);
            uint4 c2 = *(const uint4*)(ap + 16), c3 = *(const uint4*)(ap + 24);
            *(uint4*)&As[sr][sh + 0]  = c0;
            *(uint4*)&As[sr][sh + 8]  = c1;
            *(uint4*)&As[sr][sh + 16] = c2;
            *(uint4*)&As[sr][sh + 24] = c3;
        }
        {
            const unsigned short* wp = Wt + (size_t)(n0 + br) * DMODEL + k0 + bqr;
            uint4 b0 = *(const uint4*)wp;
            uint4 b1 = *(const uint4*)(wp + 8);
            *(uint4*)&Bs[br][bqr]     = b0;
            *(uint4*)&Bs[br][bqr + 8] = b1;
        }
        __syncthreads();
        #pragma unroll
        for (int s = 0; s < 2; ++s) {
            bf16x8 af[2];
            #pragma unroll
            for (int i = 0; i < 2; ++i)
                af[i] = *(const bf16x8*)&As[wave * 32 + i * 16 + lrow][s * 32 + quad * 8];
            #pragma unroll
            for (int n = 0; n < 4; ++n) {
                bf16x8 bf = *(const bf16x8*)&Bs[n * 16 + lrow][s * 32 + quad * 8];
                acc[0][n] = __builtin_amdgcn_mfma_f32_16x16x32_bf16(af[0], bf, acc[0][n], 0, 0, 0);
                acc[1][n] = __builtin_amdgcn_mfma_f32_16x16x32_bf16(af[1], bf, acc[1][n], 0, 0, 0);
            }
        }
    }

    #pragma unroll
    for (int n = 0; n < 4; ++n) {
        const int col = n0 + n * 16 + lrow;
        const float bv_ = bo[col];
        #pragma unroll
        for (int i = 0; i < 2; ++i) {
            #pragma unroll
            for (int r = 0; r < 4; ++r) {
                const int m = m0 + wave * 32 + i * 16 + quad * 4 + r;
                out[(size_t)m * DMODEL + col] = acc[i][n][r] + bv_;
            }
        }
    }
}

// ---------------------------------------------------------------------------
extern "C" void kernel_launch(void* const* d_in, const int* in_sizes, int n_in,
                              void* d_out, int out_size, void* d_ws, size_t ws_size,
                              hipStream_t stream)
{
    const float* qin = (const float*)d_in[0];
    const float* kin = (const float*)d_in[1];
    const float* vin = (const float*)d_in[2];
    const float* Wq  = (const float*)d_in[3];
    const float* bq  = (const float*)d_in[4];
    const float* Wk  = (const float*)d_in[5];
    const float* bk  = (const float*)d_in[6];
    const float* Wv  = (const float*)d_in[7];
    const float* bv  = (const float*)d_in[8];
    const float* Wo  = (const float*)d_in[9];
    const float* bo  = (const float*)d_in[10];

    unsigned short* ws = (unsigned short*)d_ws;
    float* out = (float*)d_out;

    dim3 gw(DMODEL / 32, DMODEL / 32, 4);
    wt_prep_kernel<<<gw, 256, 0, stream>>>(Wq, Wk, Wv, Wo, ws + WS_WT);

    dim3 gi(QSIZE / (256 * 8), 3);
    inp_prep_kernel<<<gi, 256, 0, stream>>>(qin, kin, vin, ws + WS_ABF);

    dim3 gp(DMODEL / 128, MTOT / 128, 3);
    qkv_mfma_kernel<<<gp, 256, 0, stream>>>(ws, bq, bk, bv);

    dim3 ga(BATCH * NH, SEQ / 64);
    attn_mfma_kernel<<<ga, 512, 0, stream>>>(ws, ws + WS_CTX);

    dim3 go(DMODEL / 64, MTOT / 128);
    out_proj_mfma_kernel<<<go, 256, 0, stream>>>(ws, bo, out);
}